// Round 1
// 168.947 us; speedup vs baseline: 1.1106x; 1.1106x over previous
//
#include <hip/hip_runtime.h>

// CapsNet dynamic routing — LDS-resident x, 7 launches.
//   prep_w: W fp32 -> Wy (s-GEMM frag order), WTd (u-GEMM frag order)
//   kA (block=batch, 1024 thr): x lives in LDS (128 KiB, x16y frag order).
//     mode 0: convert x fp32 -> LDS + xs_g (global f16, one layout only)
//     mode 1: stage xs_g->LDS, delta = u0@xT (xT frags via strided u16 LDS
//             reads), b = b_init + D0 + vb0, checkpoint b2 (fp32)
//     mode 2: stage xs_g->LDS, b = b2 + D1 + vb1  (single delta pass)
//     then: softmax over j (regs+shfl), y-GEMM from LDS, y16 write.
//   k2 (block=(j, 32 batches), 512 thr): s-GEMM (MFMA) + bias*csum, squash,
//     u-GEMM (MFMA) -> u16, or vout at final. W read once per 32 b.

#define BSZ 256

typedef _Float16 f16x8 __attribute__((ext_vector_type(8)));
typedef float f32x4 __attribute__((ext_vector_type(4)));

__device__ __forceinline__ void gload_lds16(const void* g, void* l) {
  __builtin_amdgcn_global_load_lds(
      (const __attribute__((address_space(1))) void*)g,
      (__attribute__((address_space(3))) void*)l, 16, 0, 0);
}

// ---------------------------------------------------------------------------
// prep_w: grid 32 (block=j), block 256.
// Wy  f16x8 idx (per j, 2048 vecs): kt*256 + d*4 + quad   (kt=c>>5, e=c&7)
// WTd f16x8 idx (per j, 2048 vecs): kt*1024 + cc*4 + quad (kt=d>>5, e=d&7)
// ---------------------------------------------------------------------------
__global__ __launch_bounds__(256) void prep_w(
    const float* __restrict__ W,     // [32*64][256]
    _Float16* __restrict__ Wy,
    _Float16* __restrict__ WTd)
{
  __shared__ __align__(16) float Wsh[64 * 260];
  const int j = blockIdx.x, t = threadIdx.x;

  #pragma unroll
  for (int k = 0; k < 16; ++k) {
    const int q = k * 256 + t;
    const int row = q >> 6, c4 = (q & 63) * 4;
    *reinterpret_cast<f32x4*>(&Wsh[row * 260 + c4]) =
        *reinterpret_cast<const f32x4*>(&W[((size_t)j * 64 + row) * 256 + c4]);
  }
  __syncthreads();

  {
    const int d = t & 63, quad = t >> 6;
    f16x8* out = reinterpret_cast<f16x8*>(Wy) + (size_t)j * 2048;
    #pragma unroll
    for (int kt = 0; kt < 8; ++kt) {
      const int c0 = kt * 32 + quad * 8;
      f16x8 h;
      #pragma unroll
      for (int e = 0; e < 8; ++e) h[e] = (_Float16)Wsh[d * 260 + c0 + e];
      out[kt * 256 + d * 4 + quad] = h;
    }
  }
  {
    const int cc = t;
    f16x8* out = reinterpret_cast<f16x8*>(WTd) + (size_t)j * 2048;
    #pragma unroll
    for (int h8 = 0; h8 < 8; ++h8) {
      const int kt = h8 >> 2, quad = h8 & 3;
      f16x8 h;
      #pragma unroll
      for (int e = 0; e < 8; ++e)
        h[e] = (_Float16)Wsh[(h8 * 8 + e) * 260 + cc];
      out[kt * 1024 + cc * 4 + quad] = h;
    }
  }
}

// ---------------------------------------------------------------------------
// kA: grid BSZ, block 1024 (16 waves; wave w owns column w*16+l15).
// xs (LDS) / xs_g layout, f16x8 vec idx: kk*1024 + c*4 + quad
//   (kk = i>>5, quad = (i>>3)&3, elem e = i&7); element (c,i) at f16 offset
//   F(c,i) = ((i>>5)*1024 + c*4 + ((i>>3)&3))*8 + (i&7)
// y-GEMM B-frag:  vec[kk*1024 + ii*4 + quad]          (b128, conflict-free)
// delta B-frag:   xs[F(c0+e, ii)] e=0..7               (u16 strided, 4-way)
// ---------------------------------------------------------------------------
__global__ __launch_bounds__(1024) void kA(
    const float* __restrict__ x,        // [b][c][i] fp32 (mode 0 only)
    _Float16* __restrict__ xs_g,        // frag-ordered f16 x (global copy)
    const _Float16* __restrict__ u,     // [b][j][c]  (modes 1,2)
    const float* __restrict__ vb,       // [b][j]     (modes 1,2)
    const float* __restrict__ bsrc,     // [b][j][i]  (b_init or b2)
    float* __restrict__ b2out,          // [b][j][i]  (mode 1 writes)
    _Float16* __restrict__ y16,         // [b][j][c]
    float* __restrict__ csum_ws,        // [b][j]
    int mode)
{
  __shared__ __align__(16) _Float16 xs[65536];     // 128 KiB, whole batch of x
  __shared__ __align__(16) _Float16 SB[32 * 264];  // u-frags -> softmax -> y
  __shared__ float vbs[32];
  __shared__ float csumsh[32];

  const int b = blockIdx.x, t = threadIdx.x;
  const int w = t >> 6, lane = t & 63, l15 = lane & 15, quad = lane >> 4;
  const int ii = w * 16 + l15;
  const float* bp = bsrc + (size_t)b * 8192;

  float breg[2][4];

  if (mode == 0) {
    // ---- convert own x batch: fp32 [c][i] -> LDS xs + global xs_g ----
    const float* xb = x + (size_t)b * 65536;
    f16x8* xg = reinterpret_cast<f16x8*>(xs_g) + (size_t)b * 8192;
    #pragma unroll
    for (int q = 0; q < 2; ++q) {
      const int p = q * 1024 + t;
      const int i8 = (p & 31) * 8;
      const int c4 = (p >> 5) * 4;
      const int kk = i8 >> 5, qd = (i8 >> 3) & 3;
      f32x4 v[4][2];
      #pragma unroll
      for (int s = 0; s < 4; ++s) {
        v[s][0] = *reinterpret_cast<const f32x4*>(&xb[(c4 + s) * 256 + i8]);
        v[s][1] = *reinterpret_cast<const f32x4*>(&xb[(c4 + s) * 256 + i8 + 4]);
      }
      #pragma unroll
      for (int s = 0; s < 4; ++s) {
        f16x8 h;
        #pragma unroll
        for (int e = 0; e < 4; ++e) {
          h[e] = (_Float16)v[s][0][e];
          h[4 + e] = (_Float16)v[s][1][e];
        }
        const int vi = kk * 1024 + (c4 + s) * 4 + qd;
        *reinterpret_cast<f16x8*>(&xs[vi * 8]) = h;
        xg[vi] = h;
      }
    }
  } else {
    // ---- stream xs_g -> LDS (16B/lane, linear dest: lane order == layout) --
    const f16x8* xg = reinterpret_cast<const f16x8*>(xs_g) + (size_t)b * 8192;
    #pragma unroll
    for (int it = 0; it < 8; ++it) {
      const int vi = it * 1024 + t;
      gload_lds16(xg + vi, &xs[vi * 8]);
    }
    // stage u -> SB as delta A-frags (row pad 264)
    {
      const f16x8* ug = reinterpret_cast<const f16x8*>(u + (size_t)b * 8192);
      const int jr = t >> 5, co = (t & 31) * 8;
      *reinterpret_cast<f16x8*>(&SB[jr * 264 + co]) = ug[t];
    }
    if (t < 32) vbs[t] = vb[b * 32 + t];
  }

  // hoisted b loads (overlap the staging traffic)
  #pragma unroll
  for (int mt = 0; mt < 2; ++mt)
    #pragma unroll
    for (int rr = 0; rr < 4; ++rr)
      breg[mt][rr] = bp[(mt * 16 + quad * 4 + rr) * 256 + ii];

  if (t < 32) csumsh[t] = 0.f;
  __syncthreads();  // xs + SB staged (vmcnt drained), csumsh zeroed

  if (mode != 0) {
    // ---- delta-GEMM: D[j, i=ii] = sum_c u[j,c] x[c,ii], all from LDS ----
    const int xbase = ((ii >> 5) * 1024 + ((ii >> 3) & 3)) * 8 + (ii & 7);
    f32x4 acc0 = (f32x4){0.f, 0.f, 0.f, 0.f};
    f32x4 acc1 = (f32x4){0.f, 0.f, 0.f, 0.f};
    #pragma unroll
    for (int kk = 0; kk < 8; ++kk) {
      const int ko = kk * 32 + quad * 8;
      f16x8 bf;
      #pragma unroll
      for (int e = 0; e < 8; ++e)
        bf[e] = xs[xbase + (ko + e) * 32];   // x^T frag: strided u16 reads
      f16x8 a0 = *reinterpret_cast<const f16x8*>(&SB[l15 * 264 + ko]);
      f16x8 a1 = *reinterpret_cast<const f16x8*>(&SB[(16 + l15) * 264 + ko]);
      acc0 = __builtin_amdgcn_mfma_f32_16x16x32_f16(a0, bf, acc0, 0, 0, 0);
      acc1 = __builtin_amdgcn_mfma_f32_16x16x32_f16(a1, bf, acc1, 0, 0, 0);
    }
    #pragma unroll
    for (int rr = 0; rr < 4; ++rr) {
      const int j0 = quad * 4 + rr, j1 = 16 + j0;
      breg[0][rr] += acc0[rr] + vbs[j0];
      breg[1][rr] += acc1[rr] + vbs[j1];
    }
    if (mode == 1) {
      // checkpoint b2 = b_init + D0 + vb0 (fp32: bit-identical to recompute)
      float* bo = b2out + (size_t)b * 8192;
      #pragma unroll
      for (int mt = 0; mt < 2; ++mt)
        #pragma unroll
        for (int rr = 0; rr < 4; ++rr)
          bo[(mt * 16 + quad * 4 + rr) * 256 + ii] = breg[mt][rr];
    }
    __syncthreads();  // SB u-frag reads complete before softmax overwrites SB
  }

  // ---- softmax over j (registers + shfl across quads/halves) ----
  float cc[2][4];
  {
    float m = breg[0][0];
    #pragma unroll
    for (int mt = 0; mt < 2; ++mt)
      #pragma unroll
      for (int rr = 0; rr < 4; ++rr) m = fmaxf(m, breg[mt][rr]);
    m = fmaxf(m, __shfl_xor(m, 16));
    m = fmaxf(m, __shfl_xor(m, 32));
    float s = 0.f;
    #pragma unroll
    for (int mt = 0; mt < 2; ++mt)
      #pragma unroll
      for (int rr = 0; rr < 4; ++rr) {
        float e = __expf(breg[mt][rr] - m);
        cc[mt][rr] = e; s += e;
      }
    s += __shfl_xor(s, 16);
    s += __shfl_xor(s, 32);
    const float rinv = 1.f / s;
    #pragma unroll
    for (int mt = 0; mt < 2; ++mt)
      #pragma unroll
      for (int rr = 0; rr < 4; ++rr) {
        const float cv = cc[mt][rr] * rinv;
        cc[mt][rr] = cv;
        SB[(mt * 16 + quad * 4 + rr) * 264 + ii] = (_Float16)cv;
      }
  }
  __syncthreads();  // cs (=SB) visible

  // csum[j]
  #pragma unroll
  for (int mt = 0; mt < 2; ++mt)
    #pragma unroll
    for (int rr = 0; rr < 4; ++rr) {
      float pj = cc[mt][rr];
      pj += __shfl_xor(pj, 1);
      pj += __shfl_xor(pj, 2);
      pj += __shfl_xor(pj, 4);
      pj += __shfl_xor(pj, 8);
      if (l15 == 0) atomicAdd(&csumsh[mt * 16 + quad * 4 + rr], pj);
    }

  // ---- y[j,c] = sum_i c[j,i] * x[c,i]  (both operands in LDS) ----
  f32x4 acy0 = (f32x4){0.f, 0.f, 0.f, 0.f};
  f32x4 acy1 = (f32x4){0.f, 0.f, 0.f, 0.f};
  #pragma unroll
  for (int kk = 0; kk < 8; ++kk) {
    const int ko = kk * 32 + quad * 8;
    f16x8 bf = *reinterpret_cast<const f16x8*>(&xs[(kk * 1024 + ii * 4 + quad) * 8]);
    f16x8 a0 = *reinterpret_cast<const f16x8*>(&SB[l15 * 264 + ko]);
    f16x8 a1 = *reinterpret_cast<const f16x8*>(&SB[(16 + l15) * 264 + ko]);
    acy0 = __builtin_amdgcn_mfma_f32_16x16x32_f16(a0, bf, acy0, 0, 0, 0);
    acy1 = __builtin_amdgcn_mfma_f32_16x16x32_f16(a1, bf, acy1, 0, 0, 0);
  }
  __syncthreads();  // all cs reads done before repack overwrites SB

  // repack D-layout -> SB -> coalesced f16x8 stores
  #pragma unroll
  for (int rr = 0; rr < 4; ++rr) {
    SB[(quad * 4 + rr) * 264 + ii] = (_Float16)acy0[rr];
    SB[(16 + quad * 4 + rr) * 264 + ii] = (_Float16)acy1[rr];
  }
  __syncthreads();
  {
    const int jr = t >> 5, co = (t & 31) * 8;
    *reinterpret_cast<f16x8*>(&y16[(size_t)b * 8192 + jr * 256 + co]) =
        *reinterpret_cast<const f16x8*>(&SB[jr * 264 + co]);
  }
  if (t < 32) csum_ws[b * 32 + t] = csumsh[t];
}

// ---------------------------------------------------------------------------
// k2: grid 256 = 32 j x 8 chunks of 32 batches, block 512 (8 waves).
// ---------------------------------------------------------------------------
__global__ __launch_bounds__(512) void k2(
    const _Float16* __restrict__ Wy,
    const _Float16* __restrict__ WTd,
    const float* __restrict__ bias,
    const _Float16* __restrict__ y16,   // [b][j][c]
    const float* __restrict__ csum_ws,  // [b][j]
    _Float16* __restrict__ u16,         // [b][j][c] (target buffer)
    float* __restrict__ vb_ws,          // [b][j]
    float* __restrict__ vout,           // [b][j][d]
    int final_iter)
{
  __shared__ __align__(16) _Float16 ysh[32 * 264];   // y stage, then u-repack
  __shared__ __align__(16) _Float16 vsh[32 * 72];
  __shared__ float n2sh[32];
  __shared__ float vbsh[32];
  __shared__ float csums[32];

  const int jb = blockIdx.x & 31;
  const int b0 = (blockIdx.x >> 5) * 32;
  const int t = threadIdx.x;
  const int w = t >> 6, lane = t & 63, l15 = lane & 15, quad = lane >> 4;

  #pragma unroll
  for (int p0 = 0; p0 < 2; ++p0) {
    const int p = p0 * 512 + t;
    const int bs = p >> 5, co = (p & 31) * 8;
    *reinterpret_cast<f16x8*>(&ysh[bs * 264 + co]) =
        *reinterpret_cast<const f16x8*>(
            &y16[(size_t)(b0 + bs) * 8192 + jb * 256 + co]);
  }
  if (t < 32) {
    csums[t] = csum_ws[(b0 + t) * 32 + jb];
    n2sh[t] = 0.f;
    vbsh[t] = 0.f;
  }
  __syncthreads();

  // ---- s-GEMM: wave w -> (mt = w&1, nt = w>>1) ----
  const int mt = w & 1, nt = w >> 1;
  const f16x8* Wg8 = reinterpret_cast<const f16x8*>(Wy) + (size_t)jb * 2048;
  const int d = nt * 16 + l15;
  f32x4 sacc = (f32x4){0.f, 0.f, 0.f, 0.f};
  #pragma unroll
  for (int kt = 0; kt < 8; ++kt) {
    const int ko = kt * 32 + quad * 8;
    f16x8 a = *reinterpret_cast<const f16x8*>(&ysh[(mt * 16 + l15) * 264 + ko]);
    f16x8 bf = Wg8[kt * 256 + d * 4 + quad];   // coalesced
    sacc = __builtin_amdgcn_mfma_f32_16x16x32_f16(a, bf, sacc, 0, 0, 0);
  }
  const float biasd = bias[jb * 64 + d];
  float sv[4];
  #pragma unroll
  for (int rr = 0; rr < 4; ++rr)
    sv[rr] = sacc[rr] + biasd * csums[mt * 16 + quad * 4 + rr];

  #pragma unroll
  for (int rr = 0; rr < 4; ++rr) {
    float p = sv[rr] * sv[rr];
    p += __shfl_xor(p, 1);
    p += __shfl_xor(p, 2);
    p += __shfl_xor(p, 4);
    p += __shfl_xor(p, 8);
    if (l15 == 0) atomicAdd(&n2sh[mt * 16 + quad * 4 + rr], p);
  }
  __syncthreads();

  float vv[4];
  #pragma unroll
  for (int rr = 0; rr < 4; ++rr) {
    const float n2 = n2sh[mt * 16 + quad * 4 + rr];
    const float sc = sqrtf(n2) / (1.f + n2);
    vv[rr] = sv[rr] * sc;
  }

  if (final_iter) {
    #pragma unroll
    for (int rr = 0; rr < 4; ++rr)
      vout[((size_t)(b0 + mt * 16 + quad * 4 + rr) * 32 + jb) * 64 + d] = vv[rr];
  } else {
    #pragma unroll
    for (int rr = 0; rr < 4; ++rr) {
      vsh[(mt * 16 + quad * 4 + rr) * 72 + d] = (_Float16)vv[rr];
      float p = vv[rr] * biasd;
      p += __shfl_xor(p, 1);
      p += __shfl_xor(p, 2);
      p += __shfl_xor(p, 4);
      p += __shfl_xor(p, 8);
      if (l15 == 0) atomicAdd(&vbsh[mt * 16 + quad * 4 + rr], p);
    }
    __syncthreads();   // vsh complete; ysh reads done -> reuse as u-repack
    if (t < 32) vb_ws[(b0 + t) * 32 + jb] = vbsh[t];

    // ---- u-GEMM: wave w -> (mt, ntu = (w>>1)*4 + q) ----
    const f16x8* WT8 = reinterpret_cast<const f16x8*>(WTd) + (size_t)jb * 2048;
    #pragma unroll
    for (int q = 0; q < 4; ++q) {
      const int ntu = (w >> 1) * 4 + q;
      const int cc = ntu * 16 + l15;
      f32x4 ua = (f32x4){0.f, 0.f, 0.f, 0.f};
      #pragma unroll
      for (int kt = 0; kt < 2; ++kt) {
        const int ko = kt * 32 + quad * 8;
        f16x8 a = *reinterpret_cast<const f16x8*>(&vsh[(mt * 16 + l15) * 72 + ko]);
        f16x8 bf = WT8[kt * 1024 + cc * 4 + quad];   // coalesced
        ua = __builtin_amdgcn_mfma_f32_16x16x32_f16(a, bf, ua, 0, 0, 0);
      }
      #pragma unroll
      for (int rr = 0; rr < 4; ++rr)
        ysh[(mt * 16 + quad * 4 + rr) * 264 + cc] = (_Float16)ua[rr];
    }
    __syncthreads();
    // coalesced u16 write-out
    #pragma unroll
    for (int p0 = 0; p0 < 2; ++p0) {
      const int p = p0 * 512 + t;
      const int bs = p >> 5, co = (p & 31) * 8;
      *reinterpret_cast<f16x8*>(&u16[(size_t)(b0 + bs) * 8192 + jb * 256 + co]) =
          *reinterpret_cast<const f16x8*>(&ysh[bs * 264 + co]);
    }
  }
}

// ---------------------------------------------------------------------------
extern "C" void kernel_launch(void* const* d_in, const int* in_sizes, int n_in,
                              void* d_out, int out_size, void* d_ws, size_t ws_size,
                              hipStream_t stream) {
  (void)in_sizes; (void)n_in; (void)out_size; (void)ws_size;
  const float* x      = (const float*)d_in[0];
  const float* W      = (const float*)d_in[1];
  const float* bias   = (const float*)d_in[2];
  const float* b_init = (const float*)d_in[3];
  char* ws = (char*)d_ws;

  _Float16* xs_g = (_Float16*)(ws);                             // 32 MiB
  _Float16* Wy   = (_Float16*)(ws + (32u << 20));               // 1 MiB
  _Float16* WTd  = (_Float16*)(ws + (33u << 20));               // 1 MiB
  _Float16* y16  = (_Float16*)(ws + (34u << 20));               // 4 MiB
  _Float16* u16a = (_Float16*)(ws + (38u << 20));               // 4 MiB
  _Float16* u16b = (_Float16*)(ws + (42u << 20));               // 4 MiB
  float*    b2   = (float*)(ws + (46u << 20));                  // 8 MiB
  float*    csum = (float*)(ws + (54u << 20));                  // 32 KiB
  float*    vb0  = (float*)(ws + (54u << 20) + (64u << 10));    // 32 KiB
  float*    vb1  = (float*)(ws + (54u << 20) + (128u << 10));   // 32 KiB
  float*    vout = (float*)d_out;

  prep_w<<<32, 256, 0, stream>>>(W, Wy, WTd);
  // iter 1: convert x (LDS + xs_g), softmax(b_init), y
  kA<<<BSZ, 1024, 0, stream>>>(x, xs_g, u16a, vb0, b_init, b2, y16, csum, 0);
  k2<<<256, 512, 0, stream>>>(Wy, WTd, bias, y16, csum, u16a, vb0, vout, 0);
  // iter 2: b = b_init + D(u0)+vb0, checkpoint b2
  kA<<<BSZ, 1024, 0, stream>>>(x, xs_g, u16a, vb0, b_init, b2, y16, csum, 1);
  k2<<<256, 512, 0, stream>>>(Wy, WTd, bias, y16, csum, u16b, vb1, vout, 0);
  // iter 3: b = b2 + D(u1)+vb1  (single delta pass)
  kA<<<BSZ, 1024, 0, stream>>>(x, xs_g, u16b, vb1, b2, b2, y16, csum, 2);
  k2<<<256, 512, 0, stream>>>(Wy, WTd, bias, y16, csum, u16a, vb0, vout, 1);
}